// Round 2
// baseline (1213.228 us; speedup 1.0000x reference)
//
#include <hip/hip_runtime.h>

#define NIN   1152
#define DIN   8
#define NOUTC 10
#define DOUTC 16
#define GB    4      // batches per block
#define BLOCK 384    // 6 waves; 1152/384 = 3 capsules per thread
#define KPT   3
#define NWAVES 6
#define EPSQ  1e-7f

__global__ __launch_bounds__(BLOCK, 2) void caps_route_kernel(
    const float* __restrict__ x,   // [B, NIN, DIN]
    const float* __restrict__ W,   // [NIN, NOUT, DOUT, DIN]
    float* __restrict__ out,       // [B, NOUT, DOUT]
    int ngroups)
{
    const int nout = blockIdx.x / ngroups;   // nout-major: consecutive blocks share W slice in L2
    const int bg   = blockIdx.x % ngroups;
    const int b0   = bg * GB;
    const int t    = threadIdx.x;
    const int lane = t & 63;
    const int wave = t >> 6;

    float uh[KPT][GB][DOUTC];   // 192 VGPR: u_hat, fully register-resident
    float blog[KPT][GB];        // routing logits b

    #pragma unroll
    for (int k = 0; k < KPT; ++k)
        #pragma unroll
        for (int g = 0; g < GB; ++g)
            blog[k][g] = 0.f;

    // ---- Phase 1: u_hat[i, d] = sum_e W[i, nout, d, e] * x[b, i, e] ----
    #pragma unroll
    for (int k = 0; k < KPT; ++k) {
        const int i = t + k * BLOCK;
        float xv[GB][DIN];
        #pragma unroll
        for (int g = 0; g < GB; ++g) {
            const float4* xp = reinterpret_cast<const float4*>(
                x + ((size_t)(b0 + g) * NIN + i) * DIN);
            float4 a = xp[0];
            float4 b = xp[1];
            xv[g][0] = a.x; xv[g][1] = a.y; xv[g][2] = a.z; xv[g][3] = a.w;
            xv[g][4] = b.x; xv[g][5] = b.y; xv[g][6] = b.z; xv[g][7] = b.w;
        }
        const float* wp = W + ((size_t)i * NOUTC + nout) * (DOUTC * DIN);
        #pragma unroll
        for (int d = 0; d < DOUTC; ++d) {
            const float4* w4 = reinterpret_cast<const float4*>(wp + d * DIN);
            float4 wa = w4[0];
            float4 wb = w4[1];
            #pragma unroll
            for (int g = 0; g < GB; ++g) {
                float acc;
                acc = wa.x * xv[g][0];
                acc = fmaf(wa.y, xv[g][1], acc);
                acc = fmaf(wa.z, xv[g][2], acc);
                acc = fmaf(wa.w, xv[g][3], acc);
                acc = fmaf(wb.x, xv[g][4], acc);
                acc = fmaf(wb.y, xv[g][5], acc);
                acc = fmaf(wb.z, xv[g][6], acc);
                acc = fmaf(wb.w, xv[g][7], acc);
                uh[k][g][d] = acc;
            }
        }
    }

    // ---- Phase 2: 3 routing iterations, all in registers + tiny LDS reductions ----
    __shared__ float redmax[NWAVES];
    __shared__ float redsum[NWAVES][DOUTC + 1];  // [Z, s0..s15]
    __shared__ float scal[DOUTC + 1];

    for (int it = 0; it < 3; ++it) {
        #pragma unroll
        for (int g = 0; g < GB; ++g) {
            // --- block max of logits (softmax stability) ---
            float m = blog[0][g];
            #pragma unroll
            for (int k = 1; k < KPT; ++k) m = fmaxf(m, blog[k][g]);
            #pragma unroll
            for (int off = 32; off > 0; off >>= 1)
                m = fmaxf(m, __shfl_xor(m, off));
            if (lane == 0) redmax[wave] = m;
            __syncthreads();                             // B1
            m = redmax[0];
            #pragma unroll
            for (int w = 1; w < NWAVES; ++w) m = fmaxf(m, redmax[w]);

            // --- e = exp(b - m); partial Z and s[d] = sum_i e_i * u_hat[i,d] ---
            float ek[KPT];
            float Zp = 0.f;
            #pragma unroll
            for (int k = 0; k < KPT; ++k) {
                ek[k] = expf(blog[k][g] - m);
                Zp += ek[k];
            }
            float part[DOUTC];
            #pragma unroll
            for (int d = 0; d < DOUTC; ++d) part[d] = 0.f;
            #pragma unroll
            for (int k = 0; k < KPT; ++k)
                #pragma unroll
                for (int d = 0; d < DOUTC; ++d)
                    part[d] = fmaf(ek[k], uh[k][g][d], part[d]);

            // wave-level butterfly reduce of {Z, s[16]}
            #pragma unroll
            for (int off = 32; off > 0; off >>= 1) {
                Zp += __shfl_xor(Zp, off);
                #pragma unroll
                for (int d = 0; d < DOUTC; ++d)
                    part[d] += __shfl_xor(part[d], off);
            }
            if (lane == 0) {
                redsum[wave][0] = Zp;
                #pragma unroll
                for (int d = 0; d < DOUTC; ++d) redsum[wave][1 + d] = part[d];
            }
            __syncthreads();                             // B2

            if (t < DOUTC + 1) {
                float tot = redsum[0][t];
                #pragma unroll
                for (int w = 1; w < NWAVES; ++w) tot += redsum[w][t];
                scal[t] = tot;
            }
            __syncthreads();                             // B3

            // every thread redundantly computes squash (cheap, avoids extra barrier)
            const float invZ = 1.f / scal[0];
            float s2 = 0.f;
            float sv[DOUTC];
            #pragma unroll
            for (int d = 0; d < DOUTC; ++d) {
                sv[d] = scal[1 + d] * invZ;
                s2 = fmaf(sv[d], sv[d], s2);
            }
            const float scale = (s2 / (1.f + s2)) / sqrtf(s2 + EPSQ);

            if (it < 2) {
                // agreement: b_i += <u_hat_i, v>
                #pragma unroll
                for (int k = 0; k < KPT; ++k) {
                    float dot = 0.f;
                    #pragma unroll
                    for (int d = 0; d < DOUTC; ++d)
                        dot = fmaf(uh[k][g][d], scale * sv[d], dot);
                    blog[k][g] += dot;
                }
            } else {
                if (t < DOUTC)
                    out[((size_t)(b0 + g) * NOUTC + nout) * DOUTC + t] = scale * sv[t];
            }
            // no trailing barrier needed: next round's LDS writes are fenced by B1/B2
        }
    }
}

extern "C" void kernel_launch(void* const* d_in, const int* in_sizes, int n_in,
                              void* d_out, int out_size, void* d_ws, size_t ws_size,
                              hipStream_t stream) {
    const float* x = (const float*)d_in[0];
    const float* W = (const float*)d_in[1];
    float* out = (float*)d_out;
    const int B = in_sizes[0] / (NIN * DIN);   // 1024
    const int ngroups = B / GB;                // 256
    dim3 grid(NOUTC * ngroups);
    caps_route_kernel<<<grid, BLOCK, 0, stream>>>(x, W, out, ngroups);
}

// Round 4
// 1212.548 us; speedup vs baseline: 1.0006x; 1.0006x over previous
//
#include <hip/hip_runtime.h>

#define NIN   1152
#define DIN   8
#define NOUTC 10
#define DOUTC 16
#define GB    2      // batches per block (GB*73.7KB of u_hat register state per block)
#define BLOCK 384    // 6 waves; 1152/384 = 3 capsules per thread
#define KPT   3
#define NWAVES 6
#define EPSQ  1e-7f

typedef float f32x16 __attribute__((ext_vector_type(16)));

__global__ __launch_bounds__(BLOCK, 2) void caps_route_kernel(
    const float* __restrict__ x,   // [B, NIN, DIN]
    const float* __restrict__ W,   // [NIN, NOUT, DOUT, DIN]
    float* __restrict__ out,       // [B, NOUT, DOUT]
    int ngroups)
{
    const int nout = blockIdx.x / ngroups;   // nout-major: concurrent blocks share the 590KB W slice in L2
    const int bg   = blockIdx.x % ngroups;
    const int b0   = bg * GB;
    const int t    = threadIdx.x;
    const int lane = t & 63;
    const int wave = t >> 6;

    // u_hat kept as 6 vector registers (96 VGPR) — ext_vector + constant idx => no scratch demotion
    f32x16 uh[KPT][GB];
    float blog[KPT][GB];
    #pragma unroll
    for (int k = 0; k < KPT; ++k)
        #pragma unroll
        for (int g = 0; g < GB; ++g)
            blog[k][g] = 0.f;

    // ---- Phase 1: uh[i,d] = sum_e W[i,nout,d,e] * x[b,i,e] ----
    #pragma unroll
    for (int k = 0; k < KPT; ++k) {
        const int i = t + k * BLOCK;
        float4 xa[GB], xb[GB];
        #pragma unroll
        for (int g = 0; g < GB; ++g) {
            const float4* xp = reinterpret_cast<const float4*>(
                x + ((size_t)(b0 + g) * NIN + i) * DIN);
            xa[g] = xp[0];
            xb[g] = xp[1];
        }
        const float* wp = W + ((size_t)i * NOUTC + nout) * (DOUTC * DIN);
        #pragma unroll
        for (int d = 0; d < DOUTC; ++d) {
            const float4* w4 = reinterpret_cast<const float4*>(wp + d * DIN);
            const float4 wa = w4[0];
            const float4 wb = w4[1];
            #pragma unroll
            for (int g = 0; g < GB; ++g) {
                float acc;
                acc = wa.x * xa[g].x;
                acc = fmaf(wa.y, xa[g].y, acc);
                acc = fmaf(wa.z, xa[g].z, acc);
                acc = fmaf(wa.w, xa[g].w, acc);
                acc = fmaf(wb.x, xb[g].x, acc);
                acc = fmaf(wb.y, xb[g].y, acc);
                acc = fmaf(wb.z, xb[g].z, acc);
                acc = fmaf(wb.w, xb[g].w, acc);
                uh[k][g][d] = acc;
            }
        }
    }

    // ---- Phase 2: 3 routing iterations. No max-subtract (|b| <~ 7, exp safe in fp32;
    //      softmax is shift-invariant). Deferred normalization: s = (sum e_i*uh_i)/Z. ----
    __shared__ float red[NWAVES][GB][DOUTC + 1];   // per-wave {Z, s[16]}

    for (int it = 0; it < 3; ++it) {
        f32x16 part[GB];
        float  Zp[GB];
        #pragma unroll
        for (int g = 0; g < GB; ++g) {
            Zp[g] = 0.f;
            #pragma unroll
            for (int d = 0; d < DOUTC; ++d) part[g][d] = 0.f;
            #pragma unroll
            for (int k = 0; k < KPT; ++k) {
                const float e = __expf(blog[k][g]);
                Zp[g] += e;
                part[g] = part[g] + uh[k][g] * e;   // 16 v_fma
            }
        }
        // wave-level butterfly reduce of {Z, s[16]} per g
        #pragma unroll
        for (int off = 32; off > 0; off >>= 1) {
            #pragma unroll
            for (int g = 0; g < GB; ++g) {
                Zp[g] += __shfl_xor(Zp[g], off);
                #pragma unroll
                for (int d = 0; d < DOUTC; ++d)
                    part[g][d] += __shfl_xor(part[g][d], off);
            }
        }
        if (lane == 0) {
            #pragma unroll
            for (int g = 0; g < GB; ++g) {
                red[wave][g][0] = Zp[g];
                #pragma unroll
                for (int d = 0; d < DOUTC; ++d) red[wave][g][1 + d] = part[g][d];
            }
        }
        __syncthreads();                                      // B1: red visible

        if (it < 2) {
            // every thread computes v redundantly from LDS broadcasts (all lanes same addr)
            #pragma unroll
            for (int g = 0; g < GB; ++g) {
                float Z = 0.f;
                #pragma unroll
                for (int w = 0; w < NWAVES; ++w) Z += red[w][g][0];
                const float invZ = 1.f / Z;
                f32x16 sv;
                float s2 = 0.f;
                #pragma unroll
                for (int d = 0; d < DOUTC; ++d) {
                    float sd = 0.f;
                    #pragma unroll
                    for (int w = 0; w < NWAVES; ++w) sd += red[w][g][1 + d];
                    sd *= invZ;
                    sv[d] = sd;
                    s2 = fmaf(sd, sd, s2);
                }
                const float scale = (s2 / (1.f + s2)) / sqrtf(s2 + EPSQ);
                // b_i += <uh_i, v> = scale * <uh_i, sv>
                #pragma unroll
                for (int k = 0; k < KPT; ++k) {
                    float dot = 0.f;
                    #pragma unroll
                    for (int d = 0; d < DOUTC; ++d)
                        dot = fmaf(uh[k][g][d], sv[d], dot);
                    blog[k][g] = fmaf(dot, scale, blog[k][g]);
                }
            }
            __syncthreads();                                  // B2: reads done before next it's writes
        } else {
            // final: 32 threads write v = scale * s/Z
            if (t < GB * DOUTC) {
                const int g = t >> 4;
                const int d = t & 15;
                float Z = 0.f;
                #pragma unroll
                for (int w = 0; w < NWAVES; ++w) Z += red[w][g][0];
                const float invZ = 1.f / Z;
                float s2 = 0.f;
                #pragma unroll
                for (int dd = 0; dd < DOUTC; ++dd) {
                    float sd = 0.f;
                    #pragma unroll
                    for (int w = 0; w < NWAVES; ++w) sd += red[w][g][1 + dd];
                    sd *= invZ;
                    s2 = fmaf(sd, sd, s2);
                }
                float sown = 0.f;
                #pragma unroll
                for (int w = 0; w < NWAVES; ++w) sown += red[w][g][1 + d];  // runtime d: LDS, fine
                sown *= invZ;
                const float scale = (s2 / (1.f + s2)) / sqrtf(s2 + EPSQ);
                out[((size_t)(b0 + g) * NOUTC + nout) * DOUTC + d] = sown * scale;
            }
        }
    }
}

extern "C" void kernel_launch(void* const* d_in, const int* in_sizes, int n_in,
                              void* d_out, int out_size, void* d_ws, size_t ws_size,
                              hipStream_t stream) {
    const float* x = (const float*)d_in[0];
    const float* W = (const float*)d_in[1];
    float* out = (float*)d_out;
    const int B = in_sizes[0] / (NIN * DIN);   // 1024
    const int ngroups = B / GB;                // 512
    dim3 grid(NOUTC * ngroups);                // 5120 blocks, nout-major
    caps_route_kernel<<<grid, BLOCK, 0, stream>>>(x, W, out, ngroups);
}

// Round 5
// 790.778 us; speedup vs baseline: 1.5342x; 1.5334x over previous
//
#include <hip/hip_runtime.h>

#define NIN   1152
#define DIN   8
#define NOUTC 10
#define DOUTC 16
#define GB    2      // batches per block
#define BLOCK 384    // 6 waves; 1152/384 = 3 capsules per thread
#define KPT   3
#define NWAVES 6
#define EPSQ  1e-7f

typedef float f32x16 __attribute__((ext_vector_type(16)));

// __launch_bounds__(384, 1): min 1 wave/EU. Round-4 evidence: (384, 2) forced a
// 128-VGPR cap (2 waves/EU needs 2 blocks resident -> 3 waves/EU -> 128-VGPR tier)
// and spilled ~78 floats/thread (WRITE_SIZE 615 MB). With min=1 the 6-wave block
// shape caps VGPRs at 256, which fits the ~190-reg demand with zero scratch.
__global__ __launch_bounds__(BLOCK, 1) void caps_route_kernel(
    const float* __restrict__ x,   // [B, NIN, DIN]
    const float* __restrict__ W,   // [NIN, NOUT, DOUT, DIN]
    float* __restrict__ out,       // [B, NOUT, DOUT]
    int ngroups)
{
    const int nout = blockIdx.x / ngroups;   // nout-major: concurrent blocks share the 590KB W slice in L2
    const int bg   = blockIdx.x % ngroups;
    const int b0   = bg * GB;
    const int t    = threadIdx.x;
    const int lane = t & 63;
    const int wave = t >> 6;

    f32x16 uh[KPT][GB];          // 96 VGPR of u_hat
    float blog[KPT][GB];
    #pragma unroll
    for (int k = 0; k < KPT; ++k)
        #pragma unroll
        for (int g = 0; g < GB; ++g)
            blog[k][g] = 0.f;

    // ---- Phase 1: uh[i,d] = sum_e W[i,nout,d,e] * x[b,i,e] ----
    #pragma unroll
    for (int k = 0; k < KPT; ++k) {
        const int i = t + k * BLOCK;
        float4 xa[GB], xb[GB];
        #pragma unroll
        for (int g = 0; g < GB; ++g) {
            const float4* xp = reinterpret_cast<const float4*>(
                x + ((size_t)(b0 + g) * NIN + i) * DIN);
            xa[g] = xp[0];
            xb[g] = xp[1];
        }
        const float* wp = W + ((size_t)i * NOUTC + nout) * (DOUTC * DIN);
        #pragma unroll
        for (int d = 0; d < DOUTC; ++d) {
            const float4* w4 = reinterpret_cast<const float4*>(wp + d * DIN);
            const float4 wa = w4[0];
            const float4 wb = w4[1];
            #pragma unroll
            for (int g = 0; g < GB; ++g) {
                float acc;
                acc = wa.x * xa[g].x;
                acc = fmaf(wa.y, xa[g].y, acc);
                acc = fmaf(wa.z, xa[g].z, acc);
                acc = fmaf(wa.w, xa[g].w, acc);
                acc = fmaf(wb.x, xb[g].x, acc);
                acc = fmaf(wb.y, xb[g].y, acc);
                acc = fmaf(wb.z, xb[g].z, acc);
                acc = fmaf(wb.w, xb[g].w, acc);
                uh[k][g][d] = acc;
            }
        }
    }

    // ---- Phase 2: 3 routing iterations. Softmax shift-invariant, |b| small ->
    //      no max-subtract. Deferred normalization: s = (sum e_i*uh_i)/Z. ----
    __shared__ float red[NWAVES][GB][DOUTC + 1];   // per-wave {Z, s[16]}
    __shared__ float scal[GB][DOUTC + 1];          // block totals

    for (int it = 0; it < 3; ++it) {
        // per-g weighted partials + wave butterfly (one g at a time: lower reg peak)
        #pragma unroll
        for (int g = 0; g < GB; ++g) {
            const float e0 = __expf(blog[0][g]);
            const float e1 = __expf(blog[1][g]);
            const float e2 = __expf(blog[2][g]);
            float Zp = e0 + e1 + e2;
            f32x16 part = uh[0][g] * e0 + uh[1][g] * e1 + uh[2][g] * e2;
            #pragma unroll
            for (int off = 32; off > 0; off >>= 1) {
                Zp += __shfl_xor(Zp, off);
                #pragma unroll
                for (int d = 0; d < DOUTC; ++d)
                    part[d] += __shfl_xor(part[d], off);
            }
            if (lane == 0) {
                red[wave][g][0] = Zp;
                #pragma unroll
                for (int d = 0; d < DOUTC; ++d) red[wave][g][1 + d] = part[d];
            }
        }
        __syncthreads();                           // B1: red visible

        // 34 threads sum across waves into scal
        if (t < GB * (DOUTC + 1)) {
            const int g = t / (DOUTC + 1);
            const int j = t % (DOUTC + 1);
            float acc = red[0][g][j];
            #pragma unroll
            for (int w = 1; w < NWAVES; ++w) acc += red[w][g][j];
            scal[g][j] = acc;
        }
        __syncthreads();                           // B2: scal visible
        // (next it's red writes happen after B2 -> no race with this it's red reads)

        if (it < 2) {
            #pragma unroll
            for (int g = 0; g < GB; ++g) {
                const float invZ = 1.f / scal[g][0];
                f32x16 sv;
                float s2 = 0.f;
                #pragma unroll
                for (int d = 0; d < DOUTC; ++d) {
                    const float sd = scal[g][1 + d] * invZ;   // broadcast LDS reads
                    sv[d] = sd;
                    s2 = fmaf(sd, sd, s2);
                }
                const float scale = (s2 / (1.f + s2)) / sqrtf(s2 + EPSQ);
                #pragma unroll
                for (int k = 0; k < KPT; ++k) {
                    float dot = 0.f;
                    #pragma unroll
                    for (int d = 0; d < DOUTC; ++d)
                        dot = fmaf(uh[k][g][d], sv[d], dot);
                    blog[k][g] = fmaf(dot, scale, blog[k][g]);
                }
            }
        } else {
            // final: 32 threads compute and write v = scale * s/Z
            if (t < GB * DOUTC) {
                const int g = t >> 4;
                const int d = t & 15;
                const float invZ = 1.f / scal[g][0];
                float s2 = 0.f;
                #pragma unroll
                for (int dd = 0; dd < DOUTC; ++dd) {
                    const float sd = scal[g][1 + dd] * invZ;
                    s2 = fmaf(sd, sd, s2);
                }
                const float scale = (s2 / (1.f + s2)) / sqrtf(s2 + EPSQ);
                const float sown = scal[g][1 + d] * invZ;     // runtime d: LDS read, fine
                out[((size_t)(b0 + g) * NOUTC + nout) * DOUTC + d] = sown * scale;
            }
        }
    }
}

extern "C" void kernel_launch(void* const* d_in, const int* in_sizes, int n_in,
                              void* d_out, int out_size, void* d_ws, size_t ws_size,
                              hipStream_t stream) {
    const float* x = (const float*)d_in[0];
    const float* W = (const float*)d_in[1];
    float* out = (float*)d_out;
    const int B = in_sizes[0] / (NIN * DIN);   // 1024
    const int ngroups = B / GB;                // 512
    dim3 grid(NOUTC * ngroups);                // 5120 blocks, nout-major
    caps_route_kernel<<<grid, BLOCK, 0, stream>>>(x, W, out, ngroups);
}

// Round 6
// 787.006 us; speedup vs baseline: 1.5416x; 1.0048x over previous
//
#include <hip/hip_runtime.h>

#define NIN   1152
#define DIN   8
#define NOUTC 10
#define DOUTC 16
#define GB    2      // batches per block
#define BLOCK 384    // 6 waves; 1152/384 = 3 capsules per thread
#define KPT   3
#define NWAVES 6
#define EPSQ  1e-7f

typedef float f32x16 __attribute__((ext_vector_type(16)));

// (384,1): min 1 wave/EU -> VGPR cap 256. Round-5 evidence: compiler minimized to
// 128 VGPR, leaving no room to hoist W loads -> per-d load->wait->FMA latency
// chains, 766us latency-bound (VALUBusy 12%). This version forces a 16-float4
// register buffer per (k, d-half) so ~16 loads pipeline before consumption.
__global__ __launch_bounds__(BLOCK, 1) void caps_route_kernel(
    const float* __restrict__ x,   // [B, NIN, DIN]
    const float* __restrict__ W,   // [NIN, NOUT, DOUT, DIN]
    float* __restrict__ out,       // [B, NOUT, DOUT]
    int ngroups)
{
    const int nout = blockIdx.x / ngroups;   // nout-major: concurrent blocks share the 590KB W slice in L2
    const int bg   = blockIdx.x % ngroups;
    const int b0   = bg * GB;
    const int t    = threadIdx.x;
    const int lane = t & 63;
    const int wave = t >> 6;

    f32x16 uh[KPT][GB];          // 96 VGPR of u_hat
    float blog[KPT][GB];
    #pragma unroll
    for (int k = 0; k < KPT; ++k)
        #pragma unroll
        for (int g = 0; g < GB; ++g)
            blog[k][g] = 0.f;

    // ---- Phase 1: uh[i,d] = sum_e W[i,nout,d,e] * x[b,i,e], hoisted W loads ----
    #pragma unroll
    for (int k = 0; k < KPT; ++k) {
        const int i = t + k * BLOCK;
        float4 xa[GB], xb[GB];
        #pragma unroll
        for (int g = 0; g < GB; ++g) {
            const float4* xp = reinterpret_cast<const float4*>(
                x + ((size_t)(b0 + g) * NIN + i) * DIN);
            xa[g] = xp[0];
            xb[g] = xp[1];
        }
        const float4* w4 = reinterpret_cast<const float4*>(
            W + ((size_t)i * NOUTC + nout) * (DOUTC * DIN));
        #pragma unroll
        for (int h = 0; h < 2; ++h) {
            // hoist 8 d's worth of W (16 float4 = 64 VGPR) -> 16 loads in flight
            float4 wbuf[16];
            #pragma unroll
            for (int j = 0; j < 16; ++j) wbuf[j] = w4[h * 16 + j];
            #pragma unroll
            for (int dd = 0; dd < 8; ++dd) {
                const float4 wa = wbuf[2 * dd];
                const float4 wb = wbuf[2 * dd + 1];
                #pragma unroll
                for (int g = 0; g < GB; ++g) {
                    float acc;
                    acc = wa.x * xa[g].x;
                    acc = fmaf(wa.y, xa[g].y, acc);
                    acc = fmaf(wa.z, xa[g].z, acc);
                    acc = fmaf(wa.w, xa[g].w, acc);
                    acc = fmaf(wb.x, xb[g].x, acc);
                    acc = fmaf(wb.y, xb[g].y, acc);
                    acc = fmaf(wb.z, xb[g].z, acc);
                    acc = fmaf(wb.w, xb[g].w, acc);
                    uh[k][g][h * 8 + dd] = acc;
                }
            }
        }
    }

    // ---- Phase 2: 3 routing iterations (identical to round-5 passing version) ----
    __shared__ float red[NWAVES][GB][DOUTC + 1];   // per-wave {Z, s[16]}
    __shared__ float scal[GB][DOUTC + 1];          // block totals

    for (int it = 0; it < 3; ++it) {
        #pragma unroll
        for (int g = 0; g < GB; ++g) {
            const float e0 = __expf(blog[0][g]);
            const float e1 = __expf(blog[1][g]);
            const float e2 = __expf(blog[2][g]);
            float Zp = e0 + e1 + e2;
            f32x16 part = uh[0][g] * e0 + uh[1][g] * e1 + uh[2][g] * e2;
            #pragma unroll
            for (int off = 32; off > 0; off >>= 1) {
                Zp += __shfl_xor(Zp, off);
                #pragma unroll
                for (int d = 0; d < DOUTC; ++d)
                    part[d] += __shfl_xor(part[d], off);
            }
            if (lane == 0) {
                red[wave][g][0] = Zp;
                #pragma unroll
                for (int d = 0; d < DOUTC; ++d) red[wave][g][1 + d] = part[d];
            }
        }
        __syncthreads();                           // B1: red visible

        if (t < GB * (DOUTC + 1)) {
            const int g = t / (DOUTC + 1);
            const int j = t % (DOUTC + 1);
            float acc = red[0][g][j];
            #pragma unroll
            for (int w = 1; w < NWAVES; ++w) acc += red[w][g][j];
            scal[g][j] = acc;
        }
        __syncthreads();                           // B2: scal visible

        if (it < 2) {
            #pragma unroll
            for (int g = 0; g < GB; ++g) {
                const float invZ = 1.f / scal[g][0];
                f32x16 sv;
                float s2 = 0.f;
                #pragma unroll
                for (int d = 0; d < DOUTC; ++d) {
                    const float sd = scal[g][1 + d] * invZ;   // broadcast LDS reads
                    sv[d] = sd;
                    s2 = fmaf(sd, sd, s2);
                }
                const float scale = (s2 / (1.f + s2)) / sqrtf(s2 + EPSQ);
                #pragma unroll
                for (int k = 0; k < KPT; ++k) {
                    float dot = 0.f;
                    #pragma unroll
                    for (int d = 0; d < DOUTC; ++d)
                        dot = fmaf(uh[k][g][d], sv[d], dot);
                    blog[k][g] = fmaf(dot, scale, blog[k][g]);
                }
            }
        } else {
            if (t < GB * DOUTC) {
                const int g = t >> 4;
                const int d = t & 15;
                const float invZ = 1.f / scal[g][0];
                float s2 = 0.f;
                #pragma unroll
                for (int dd = 0; dd < DOUTC; ++dd) {
                    const float sd = scal[g][1 + dd] * invZ;
                    s2 = fmaf(sd, sd, s2);
                }
                const float scale = (s2 / (1.f + s2)) / sqrtf(s2 + EPSQ);
                const float sown = scal[g][1 + d] * invZ;
                out[((size_t)(b0 + g) * NOUTC + nout) * DOUTC + d] = sown * scale;
            }
        }
    }
}

extern "C" void kernel_launch(void* const* d_in, const int* in_sizes, int n_in,
                              void* d_out, int out_size, void* d_ws, size_t ws_size,
                              hipStream_t stream) {
    const float* x = (const float*)d_in[0];
    const float* W = (const float*)d_in[1];
    float* out = (float*)d_out;
    const int B = in_sizes[0] / (NIN * DIN);   // 1024
    const int ngroups = B / GB;                // 512
    dim3 grid(NOUTC * ngroups);                // 5120 blocks, nout-major
    caps_route_kernel<<<grid, BLOCK, 0, stream>>>(x, W, out, ngroups);
}

// Round 7
// 786.140 us; speedup vs baseline: 1.5433x; 1.0011x over previous
//
#include <hip/hip_runtime.h>

#define NIN   1152
#define DIN   8
#define NOUTC 10
#define DOUTC 16
#define EPSQ  1e-7f

typedef float f32x16 __attribute__((ext_vector_type(16)));
typedef _Float16 half8 __attribute__((ext_vector_type(8)));

// ======================= Kernel A: u_hat producer (fp16) =======================
// Tiles: b-tile=256, i-tile=8. W-tile (41KB) transposed into LDS once, reused by
// all 256 b's. Thread (ii=t&7, bg=t>>3) computes capsules i0+ii for 8 batches.
// uh layout: [B][NOUT][2 dh][NIN][8] halfs -> 16-B contiguous stores, and 36-KB
// contiguous per-(b,n) slices for kernel B.
#define A_IT 8
#define A_BT 256
#define A_THREADS 256

__global__ __launch_bounds__(A_THREADS, 1) void caps_uhat_kernel(
    const float* __restrict__ x,   // [B, NIN, DIN]
    const float* __restrict__ W,   // [NIN, NOUT, DOUT, DIN]
    _Float16* __restrict__ uh)
{
    const int btile = blockIdx.x / (NIN / A_IT);
    const int itile = blockIdx.x % (NIN / A_IT);
    const int b0 = btile * A_BT;
    const int i0 = itile * A_IT;
    const int tid = threadIdx.x;

    // Wt[nd][ii*8+e]: ii-stride 32B -> 2-way bank conflict on b128 reads (free, m136)
    __shared__ float Wt[NOUTC * DOUTC][A_IT * DIN];   // [160][64] = 40 KB

    {   // stage + transpose W[i0:i0+8] (contiguous 10240 floats)
        const float4* wsrc = (const float4*)(W + (size_t)i0 * NOUTC * DOUTC * DIN);
        float4* wdst = (float4*)&Wt[0][0];
        #pragma unroll
        for (int j = 0; j < 10; ++j) {
            const int c  = tid + j * A_THREADS;   // 0..2559
            const int i  = c / 320;               // capsule within tile
            const int r  = c - i * 320;
            const int nd = r >> 1;
            const int eh = r & 1;
            wdst[nd * 16 + i * 2 + eh] = wsrc[c];
        }
    }
    __syncthreads();

    const int ii = tid & 7;
    const int bg = tid >> 3;
    const int i  = i0 + ii;

    // x for this thread's 8 batches: 16 independent dwordx4 loads up front (MLP)
    float4 xa[8], xb[8];
    #pragma unroll
    for (int p = 0; p < 8; ++p) {
        const int b = b0 + bg + p * 32;
        const float4* xp = (const float4*)(x + ((size_t)b * NIN + i) * DIN);
        xa[p] = xp[0];
        xb[p] = xp[1];
    }

    #pragma unroll
    for (int n = 0; n < NOUTC; ++n) {
        #pragma unroll
        for (int dh = 0; dh < 2; ++dh) {
            float acc[8][8];
            #pragma unroll
            for (int d8 = 0; d8 < 8; ++d8) {
                const int nd = n * DOUTC + dh * 8 + d8;
                const float4 w0 = *(const float4*)&Wt[nd][ii * 8];
                const float4 w1 = *(const float4*)&Wt[nd][ii * 8 + 4];
                #pragma unroll
                for (int p = 0; p < 8; ++p) {
                    float a;
                    a = w0.x * xa[p].x;
                    a = fmaf(w0.y, xa[p].y, a);
                    a = fmaf(w0.z, xa[p].z, a);
                    a = fmaf(w0.w, xa[p].w, a);
                    a = fmaf(w1.x, xb[p].x, a);
                    a = fmaf(w1.y, xb[p].y, a);
                    a = fmaf(w1.z, xb[p].z, a);
                    a = fmaf(w1.w, xb[p].w, a);
                    acc[p][d8] = a;
                }
            }
            #pragma unroll
            for (int p = 0; p < 8; ++p) {
                const int b = b0 + bg + p * 32;
                half8 hv;
                #pragma unroll
                for (int j = 0; j < 8; ++j) hv[j] = (_Float16)acc[p][j];
                *(half8*)(uh + ((((size_t)b * NOUTC + n) * 2 + dh) * NIN + i) * 8) = hv;
            }
        }
    }
}

// ======================= Kernel B: routing consumer =======================
// One block per (b, nout). Stage the contiguous 36-KB uh slice -> LDS (coalesced,
// HBM-bound 377 MB total), lift 3 capsules/thread to regs, then the verified
// register-resident routing (round-5 structure, GB=1).
#define B_THREADS 384
#define B_WAVES 6
#define B_KPT 3

__global__ __launch_bounds__(B_THREADS, 1) void caps_route2_kernel(
    const _Float16* __restrict__ uh, float* __restrict__ out)
{
    const int bid = blockIdx.x;          // = b*NOUTC + n, matches out layout
    const int t = threadIdx.x;
    const int lane = t & 63;
    const int wave = t >> 6;

    __shared__ _Float16 U[2 * NIN * 8];          // 36 KB
    __shared__ float red[B_WAVES][DOUTC + 1];
    __shared__ float scal[DOUTC + 1];

    {   // stage: 2304 float4 / 384 threads = 6 each
        const float4* src = (const float4*)(uh + (size_t)bid * (2 * NIN * 8));
        float4* dst = (float4*)U;
        #pragma unroll
        for (int j = 0; j < 6; ++j)
            dst[t + j * B_THREADS] = src[t + j * B_THREADS];
    }
    __syncthreads();

    f32x16 uhr[B_KPT];
    #pragma unroll
    for (int k = 0; k < B_KPT; ++k) {
        const int i = t + k * B_THREADS;
        const half8 lo = *(const half8*)&U[i * 8];              // dh=0: d 0..7
        const half8 hi = *(const half8*)&U[NIN * 8 + i * 8];    // dh=1: d 8..15
        #pragma unroll
        for (int j = 0; j < 8; ++j) {
            uhr[k][j] = (float)lo[j];
            uhr[k][8 + j] = (float)hi[j];
        }
    }

    float blog[B_KPT] = {0.f, 0.f, 0.f};

    for (int it = 0; it < 3; ++it) {
        const float e0 = __expf(blog[0]);
        const float e1 = __expf(blog[1]);
        const float e2 = __expf(blog[2]);
        float Zp = e0 + e1 + e2;
        f32x16 part = uhr[0] * e0 + uhr[1] * e1 + uhr[2] * e2;
        #pragma unroll
        for (int off = 32; off > 0; off >>= 1) {
            Zp += __shfl_xor(Zp, off);
            #pragma unroll
            for (int d = 0; d < DOUTC; ++d)
                part[d] += __shfl_xor(part[d], off);
        }
        if (lane == 0) {
            red[wave][0] = Zp;
            #pragma unroll
            for (int d = 0; d < DOUTC; ++d) red[wave][1 + d] = part[d];
        }
        __syncthreads();                          // B1: red visible

        if (t < DOUTC + 1) {
            float a = red[0][t];
            #pragma unroll
            for (int w = 1; w < B_WAVES; ++w) a += red[w][t];
            scal[t] = a;
        }
        __syncthreads();                          // B2: scal visible

        if (it < 2) {
            const float invZ = 1.f / scal[0];
            f32x16 sv;
            float s2 = 0.f;
            #pragma unroll
            for (int d = 0; d < DOUTC; ++d) {
                const float sd = scal[1 + d] * invZ;
                sv[d] = sd;
                s2 = fmaf(sd, sd, s2);
            }
            const float scale = (s2 / (1.f + s2)) / sqrtf(s2 + EPSQ);
            #pragma unroll
            for (int k = 0; k < B_KPT; ++k) {
                float dot = 0.f;
                #pragma unroll
                for (int d = 0; d < DOUTC; ++d)
                    dot = fmaf(uhr[k][d], sv[d], dot);
                blog[k] = fmaf(dot, scale, blog[k]);
            }
        } else {
            if (t < DOUTC) {
                const float invZ = 1.f / scal[0];
                float s2 = 0.f;
                #pragma unroll
                for (int dd = 0; dd < DOUTC; ++dd) {
                    const float sd = scal[1 + dd] * invZ;
                    s2 = fmaf(sd, sd, s2);
                }
                const float scale = (s2 / (1.f + s2)) / sqrtf(s2 + EPSQ);
                out[(size_t)bid * DOUTC + t] = scal[1 + t] * invZ * scale;
            }
        }
    }
}

// ================== Fallback: round-6 fused kernel (passing, 787us) ==================
#define GB    2
#define BLOCK 384
#define KPT   3
#define NWAVES 6

__global__ __launch_bounds__(BLOCK, 1) void caps_route_kernel(
    const float* __restrict__ x, const float* __restrict__ W,
    float* __restrict__ out, int ngroups)
{
    const int nout = blockIdx.x / ngroups;
    const int bg   = blockIdx.x % ngroups;
    const int b0   = bg * GB;
    const int t    = threadIdx.x;
    const int lane = t & 63;
    const int wave = t >> 6;

    f32x16 uh[KPT][GB];
    float blog[KPT][GB];
    #pragma unroll
    for (int k = 0; k < KPT; ++k)
        #pragma unroll
        for (int g = 0; g < GB; ++g)
            blog[k][g] = 0.f;

    #pragma unroll
    for (int k = 0; k < KPT; ++k) {
        const int i = t + k * BLOCK;
        float4 xa[GB], xb[GB];
        #pragma unroll
        for (int g = 0; g < GB; ++g) {
            const float4* xp = reinterpret_cast<const float4*>(
                x + ((size_t)(b0 + g) * NIN + i) * DIN);
            xa[g] = xp[0];
            xb[g] = xp[1];
        }
        const float4* w4 = reinterpret_cast<const float4*>(
            W + ((size_t)i * NOUTC + nout) * (DOUTC * DIN));
        #pragma unroll
        for (int d = 0; d < DOUTC; ++d) {
            const float4 wa = w4[2 * d];
            const float4 wb = w4[2 * d + 1];
            #pragma unroll
            for (int g = 0; g < GB; ++g) {
                float acc;
                acc = wa.x * xa[g].x;
                acc = fmaf(wa.y, xa[g].y, acc);
                acc = fmaf(wa.z, xa[g].z, acc);
                acc = fmaf(wa.w, xa[g].w, acc);
                acc = fmaf(wb.x, xb[g].x, acc);
                acc = fmaf(wb.y, xb[g].y, acc);
                acc = fmaf(wb.z, xb[g].z, acc);
                acc = fmaf(wb.w, xb[g].w, acc);
                uh[k][g][d] = acc;
            }
        }
    }

    __shared__ float red2[NWAVES][GB][DOUTC + 1];
    __shared__ float scal2[GB][DOUTC + 1];

    for (int it = 0; it < 3; ++it) {
        #pragma unroll
        for (int g = 0; g < GB; ++g) {
            const float e0 = __expf(blog[0][g]);
            const float e1 = __expf(blog[1][g]);
            const float e2 = __expf(blog[2][g]);
            float Zp = e0 + e1 + e2;
            f32x16 part = uh[0][g] * e0 + uh[1][g] * e1 + uh[2][g] * e2;
            #pragma unroll
            for (int off = 32; off > 0; off >>= 1) {
                Zp += __shfl_xor(Zp, off);
                #pragma unroll
                for (int d = 0; d < DOUTC; ++d)
                    part[d] += __shfl_xor(part[d], off);
            }
            if (lane == 0) {
                red2[wave][g][0] = Zp;
                #pragma unroll
                for (int d = 0; d < DOUTC; ++d) red2[wave][g][1 + d] = part[d];
            }
        }
        __syncthreads();

        if (t < GB * (DOUTC + 1)) {
            const int g = t / (DOUTC + 1);
            const int j = t % (DOUTC + 1);
            float acc = red2[0][g][j];
            #pragma unroll
            for (int w = 1; w < NWAVES; ++w) acc += red2[w][g][j];
            scal2[g][j] = acc;
        }
        __syncthreads();

        if (it < 2) {
            #pragma unroll
            for (int g = 0; g < GB; ++g) {
                const float invZ = 1.f / scal2[g][0];
                f32x16 sv;
                float s2 = 0.f;
                #pragma unroll
                for (int d = 0; d < DOUTC; ++d) {
                    const float sd = scal2[g][1 + d] * invZ;
                    sv[d] = sd;
                    s2 = fmaf(sd, sd, s2);
                }
                const float scale = (s2 / (1.f + s2)) / sqrtf(s2 + EPSQ);
                #pragma unroll
                for (int k = 0; k < KPT; ++k) {
                    float dot = 0.f;
                    #pragma unroll
                    for (int d = 0; d < DOUTC; ++d)
                        dot = fmaf(uh[k][g][d], sv[d], dot);
                    blog[k][g] = fmaf(dot, scale, blog[k][g]);
                }
            }
        } else {
            if (t < GB * DOUTC) {
                const int g = t >> 4;
                const int d = t & 15;
                const float invZ = 1.f / scal2[g][0];
                float s2 = 0.f;
                #pragma unroll
                for (int dd = 0; dd < DOUTC; ++dd) {
                    const float sd = scal2[g][1 + dd] * invZ;
                    s2 = fmaf(sd, sd, s2);
                }
                const float scale = (s2 / (1.f + s2)) / sqrtf(s2 + EPSQ);
                out[((size_t)(b0 + g) * NOUTC + nout) * DOUTC + d] =
                    scal2[g][1 + d] * invZ * scale;
            }
        }
    }
}

extern "C" void kernel_launch(void* const* d_in, const int* in_sizes, int n_in,
                              void* d_out, int out_size, void* d_ws, size_t ws_size,
                              hipStream_t stream) {
    const float* x = (const float*)d_in[0];
    const float* W = (const float*)d_in[1];
    float* out = (float*)d_out;
    const int B = in_sizes[0] / (NIN * DIN);   // 1024
    const size_t UH_BYTES = (size_t)B * NOUTC * 2 * NIN * 8 * sizeof(_Float16); // 377 MB

    if (ws_size >= UH_BYTES && (B % A_BT) == 0) {
        _Float16* uhbuf = (_Float16*)d_ws;
        dim3 gridA((B / A_BT) * (NIN / A_IT));              // 576
        caps_uhat_kernel<<<gridA, A_THREADS, 0, stream>>>(x, W, uhbuf);
        dim3 gridB(B * NOUTC);                              // 10240
        caps_route2_kernel<<<gridB, B_THREADS, 0, stream>>>(uhbuf, out);
    } else {
        const int ngroups = B / GB;
        caps_route_kernel<<<dim3(NOUTC * ngroups), BLOCK, 0, stream>>>(x, W, out, ngroups);
    }
}

// Round 10
// 781.910 us; speedup vs baseline: 1.5516x; 1.0054x over previous
//
#include <hip/hip_runtime.h>

#define NIN   1152
#define DIN   8
#define NOUTC 10
#define DOUTC 16
#define GB    2      // batches per block
#define BLOCK 384    // 6 waves; 1152/384 = 3 capsules per thread
#define KPT   3
#define NWAVES 6
#define EPSQ  1e-7f

typedef float    f32x16 __attribute__((ext_vector_type(16)));
typedef _Float16 f16x16 __attribute__((ext_vector_type(16)));

// Round 5/6 evidence: compiler pins this kernel at 128 VGPR; fp32 uh (96 VGPR)
// left ~3 W-loads in flight -> latency-bound 786us. This version stores uh as
// fp16 (48 VGPR), freeing ~48 regs under the same cap for ~8-16 in-flight W
// loads (explicit 8xfloat4 buffer per quarter-pass).
__global__ __launch_bounds__(BLOCK, 1) void caps_route_kernel(
    const float* __restrict__ x,   // [B, NIN, DIN]
    const float* __restrict__ W,   // [NIN, NOUT, DOUT, DIN]
    float* __restrict__ out,       // [B, NOUT, DOUT]
    int ngroups)
{
    const int nout = blockIdx.x / ngroups;   // nout-major: concurrent blocks share W slice in L2
    const int bg   = blockIdx.x % ngroups;
    const int b0   = bg * GB;
    const int t    = threadIdx.x;
    const int lane = t & 63;
    const int wave = t >> 6;

    f16x16 uh[KPT][GB];          // 48 VGPR of u_hat (fp16)
    float blog[KPT][GB];
    #pragma unroll
    for (int k = 0; k < KPT; ++k)
        #pragma unroll
        for (int g = 0; g < GB; ++g)
            blog[k][g] = 0.f;

    // ---- Phase 1: uh[i,d] = sum_e W[i,nout,d,e] * x[b,i,e] ----
    #pragma unroll
    for (int k = 0; k < KPT; ++k) {
        const int i = t + k * BLOCK;
        float4 xa[GB], xb[GB];
        #pragma unroll
        for (int g = 0; g < GB; ++g) {
            const float4* xp = reinterpret_cast<const float4*>(
                x + ((size_t)(b0 + g) * NIN + i) * DIN);
            xa[g] = xp[0];
            xb[g] = xp[1];
        }
        const float4* w4 = reinterpret_cast<const float4*>(
            W + ((size_t)i * NOUTC + nout) * (DOUTC * DIN));
        #pragma unroll
        for (int q = 0; q < 4; ++q) {        // 4 d's per quarter-pass
            float4 wbuf[8];                   // 8 loads in flight (32 VGPR)
            #pragma unroll
            for (int j = 0; j < 8; ++j) wbuf[j] = w4[q * 8 + j];
            #pragma unroll
            for (int dd = 0; dd < 4; ++dd) {
                const float4 wa = wbuf[2 * dd];
                const float4 wb = wbuf[2 * dd + 1];
                #pragma unroll
                for (int g = 0; g < GB; ++g) {
                    float a;
                    a = wa.x * xa[g].x;
                    a = fmaf(wa.y, xa[g].y, a);
                    a = fmaf(wa.z, xa[g].z, a);
                    a = fmaf(wa.w, xa[g].w, a);
                    a = fmaf(wb.x, xb[g].x, a);
                    a = fmaf(wb.y, xb[g].y, a);
                    a = fmaf(wb.z, xb[g].z, a);
                    a = fmaf(wb.w, xb[g].w, a);
                    uh[k][g][q * 4 + dd] = (_Float16)a;
                }
            }
        }
    }

    // ---- Phase 2: 3 routing iterations (round-5 verified structure, fp16 unpack) ----
    __shared__ float red[NWAVES][GB][DOUTC + 1];   // per-wave {Z, s[16]}
    __shared__ float scal[GB][DOUTC + 1];          // block totals

    for (int it = 0; it < 3; ++it) {
        #pragma unroll
        for (int g = 0; g < GB; ++g) {
            const float e0 = __expf(blog[0][g]);
            const float e1 = __expf(blog[1][g]);
            const float e2 = __expf(blog[2][g]);
            float Zp = e0 + e1 + e2;
            f32x16 part;
            #pragma unroll
            for (int d = 0; d < DOUTC; ++d)
                part[d] = (float)uh[0][g][d] * e0;
            #pragma unroll
            for (int d = 0; d < DOUTC; ++d)
                part[d] = fmaf((float)uh[1][g][d], e1, part[d]);
            #pragma unroll
            for (int d = 0; d < DOUTC; ++d)
                part[d] = fmaf((float)uh[2][g][d], e2, part[d]);
            #pragma unroll
            for (int off = 32; off > 0; off >>= 1) {
                Zp += __shfl_xor(Zp, off);
                #pragma unroll
                for (int d = 0; d < DOUTC; ++d)
                    part[d] += __shfl_xor(part[d], off);
            }
            if (lane == 0) {
                red[wave][g][0] = Zp;
                #pragma unroll
                for (int d = 0; d < DOUTC; ++d) red[wave][g][1 + d] = part[d];
            }
        }
        __syncthreads();                           // B1: red visible

        if (t < GB * (DOUTC + 1)) {
            const int g = t / (DOUTC + 1);
            const int j = t % (DOUTC + 1);
            float acc = red[0][g][j];
            #pragma unroll
            for (int w = 1; w < NWAVES; ++w) acc += red[w][g][j];
            scal[g][j] = acc;
        }
        __syncthreads();                           // B2: scal visible

        if (it < 2) {
            #pragma unroll
            for (int g = 0; g < GB; ++g) {
                const float invZ = 1.f / scal[g][0];
                f32x16 sv;
                float s2 = 0.f;
                #pragma unroll
                for (int d = 0; d < DOUTC; ++d) {
                    const float sd = scal[g][1 + d] * invZ;   // broadcast LDS reads
                    sv[d] = sd;
                    s2 = fmaf(sd, sd, s2);
                }
                const float scale = (s2 / (1.f + s2)) / sqrtf(s2 + EPSQ);
                #pragma unroll
                for (int k = 0; k < KPT; ++k) {
                    float dot = 0.f;
                    #pragma unroll
                    for (int d = 0; d < DOUTC; ++d)
                        dot = fmaf((float)uh[k][g][d], sv[d], dot);
                    blog[k][g] = fmaf(dot, scale, blog[k][g]);
                }
            }
        } else {
            if (t < GB * DOUTC) {
                const int g = t >> 4;
                const int d = t & 15;
                const float invZ = 1.f / scal[g][0];
                float s2 = 0.f;
                #pragma unroll
                for (int dd = 0; dd < DOUTC; ++dd) {
                    const float sd = scal[g][1 + dd] * invZ;
                    s2 = fmaf(sd, sd, s2);
                }
                const float scale = (s2 / (1.f + s2)) / sqrtf(s2 + EPSQ);
                out[((size_t)(b0 + g) * NOUTC + nout) * DOUTC + d] =
                    scal[g][1 + d] * invZ * scale;
            }
        }
    }
}

extern "C" void kernel_launch(void* const* d_in, const int* in_sizes, int n_in,
                              void* d_out, int out_size, void* d_ws, size_t ws_size,
                              hipStream_t stream) {
    const float* x = (const float*)d_in[0];
    const float* W = (const float*)d_in[1];
    float* out = (float*)d_out;
    const int B = in_sizes[0] / (NIN * DIN);   // 1024
    const int ngroups = B / GB;                // 512
    caps_route_kernel<<<dim3(NOUTC * ngroups), BLOCK, 0, stream>>>(x, W, out, ngroups);
}